// Round 1
// baseline (251.027 us; speedup 1.0000x reference)
//
#include <hip/hip_runtime.h>

typedef unsigned short ushort_t;
typedef __attribute__((ext_vector_type(8))) short short8;
typedef __attribute__((ext_vector_type(4))) float f32x4;
typedef __attribute__((ext_vector_type(2))) unsigned uint2v;
typedef __attribute__((ext_vector_type(4))) unsigned uint4v;

#define LOG2E 1.44269504088896f

// async global->LDS, 16B per lane. LDS dest must be wave-uniform base + lane*16.
__device__ __forceinline__ void async16(const void* g, void* l) {
  __builtin_amdgcn_global_load_lds(
      (const __attribute__((address_space(1))) void*)g,
      (__attribute__((address_space(3))) void*)l, 16, 0, 0);
}

__device__ __forceinline__ ushort_t f2bf(float f) {
  union { float f; unsigned u; } x; x.f = f;
  unsigned u = x.u;
  u += 0x7fffu + ((u >> 16) & 1u);
  return (ushort_t)(u >> 16);
}

__device__ __forceinline__ float bf2f(ushort_t w) {
  union { unsigned u; float f; } x; x.u = ((unsigned)w) << 16;
  return x.f;
}

__device__ __forceinline__ short8 u4s8(uint4v u) { union { uint4v a; short8 b; } c; c.a = u; return c.b; }
__device__ __forceinline__ uint4v s8u4(short8 s) { union { short8 a; uint4v b; } c; c.a = s; return c.b; }
__device__ __forceinline__ unsigned fu(float f) { union { float a; unsigned b; } c; c.a = f; return c.b; }

// ------------- merged split ingest: cur+hid fp32 -> (hi, lo) bf16 -------------
__global__ __launch_bounds__(256) void split_all(const float* __restrict__ cur,
                                                 const float* __restrict__ hid,
                                                 ushort_t* __restrict__ ch,
                                                 ushort_t* __restrict__ cl,
                                                 ushort_t* __restrict__ hh,
                                                 ushort_t* __restrict__ hl) {
  int i = blockIdx.x * 256 + threadIdx.x;       // 0 .. 2*524288-1
  const float* src;
  ushort_t *hi, *lo;
  int j;
  if (i < 524288) { src = cur; hi = ch; lo = cl; j = i; }
  else            { src = hid; hi = hh; lo = hl; j = i - 524288; }
  const f32x4* s = (const f32x4*)src;
  f32x4 a = s[j * 2], b = s[j * 2 + 1];
  short8 oh, ol;
  #pragma unroll
  for (int k = 0; k < 4; k++) {
    ushort_t h = f2bf(a[k]); oh[k] = (short)h; ol[k] = (short)f2bf(a[k] - bf2f(h));
    h = f2bf(b[k]); oh[k + 4] = (short)h; ol[k + 4] = (short)f2bf(b[k] - bf2f(h));
  }
  ((short8*)hi)[j] = oh;
  ((short8*)lo)[j] = ol;
}

// ------- merged weight transpose+split: 3 matrices in one launch -------
__global__ __launch_bounds__(256) void transpose_all(const float* __restrict__ Wq,
                                                     const float* __restrict__ Wkv,
                                                     const float* __restrict__ Wo,
                                                     ushort_t* __restrict__ qh, ushort_t* __restrict__ ql,
                                                     ushort_t* __restrict__ kvh, ushort_t* __restrict__ kvl,
                                                     ushort_t* __restrict__ oh, ushort_t* __restrict__ ol) {
  __shared__ float tile[32][33];
  int bid = blockIdx.x;
  const float* src; ushort_t *dh, *dl; int Nn, bx, by;
  const int K = 512;
  if (bid < 256)      { src = Wq;  dh = qh;  dl = ql;  Nn = 512;  bx = (bid & 15) * 32; by = (bid >> 4) * 32; }
  else if (bid < 768) { int b = bid - 256; src = Wkv; dh = kvh; dl = kvl; Nn = 1024; bx = (b & 31) * 32; by = (b >> 5) * 32; }
  else                { int b = bid - 768; src = Wo;  dh = oh;  dl = ol;  Nn = 512;  bx = (b & 15) * 32; by = (b >> 4) * 32; }
  int tx = threadIdx.x & 31, ty = threadIdx.x >> 5;   // (32, 8)
  #pragma unroll
  for (int i = 0; i < 32; i += 8)
    tile[ty + i][tx] = src[(size_t)(by + ty + i) * Nn + bx + tx];
  __syncthreads();
  #pragma unroll
  for (int i = 0; i < 32; i += 8) {
    float v = tile[tx][ty + i];
    ushort_t h = f2bf(v);
    size_t idx = (size_t)(bx + ty + i) * K + by + tx;
    dh[idx] = h;
    dl[idx] = f2bf(v - bf2f(h));
  }
}

// ---- split GEMM: C = (Ah+Al)[M][K] @ (Bh+Bl)[Nn][K]^T, 3-product bf16x3 ----
// BM = MT*32, BN = TN*32. 4 waves (2x2); wave tile = (MT*16) x (TN*16).
// EPI 0: C -> (o_hi,o_lo) q-layout [B*H][N][D]
// EPI 1: col<512 -> (o_hi,o_lo) k-layout; col>=512 -> o_vt bf16 [B*H][D][N]
// EPI 2: outf fp32 row-major [M][ldo]  (final output)
template<int EPI, int MT, int TN>
__global__ __launch_bounds__(256) void gemm3_bt(const ushort_t* __restrict__ Ah,
                                                const ushort_t* __restrict__ Al,
                                                const ushort_t* __restrict__ Bh,
                                                const ushort_t* __restrict__ Bl,
                                                ushort_t* __restrict__ o_hi,
                                                ushort_t* __restrict__ o_lo,
                                                ushort_t* __restrict__ o_vt,
                                                float* __restrict__ outf,
                                                int K, int ldo) {
  constexpr int BM = MT * 32;
  constexpr int BN = TN * 32;
  __shared__ __align__(16) ushort_t Ash[BM * 32];
  __shared__ __align__(16) ushort_t Asl[BM * 32];
  __shared__ __align__(16) ushort_t Bsh[BN * 32];
  __shared__ __align__(16) ushort_t Bsl[BN * 32];
  const int tid = threadIdx.x;
  const int wave = tid >> 6, lane = tid & 63;
  const int wm = (wave >> 1) * (MT * 16), wn = (wave & 1) * (TN * 16);
  const int m0 = blockIdx.y * BM, n0 = blockIdx.x * BN;
  const int lrow = lane & 15, lq = lane >> 4;

  f32x4 acc[MT][TN];
  const f32x4 z = {0.f, 0.f, 0.f, 0.f};
  #pragma unroll
  for (int i = 0; i < MT; i++)
    #pragma unroll
    for (int j = 0; j < TN; j++) acc[i][j] = z;

  for (int k0 = 0; k0 < K; k0 += 32) {
    __syncthreads();
    #pragma unroll
    for (int i = 0; i < MT / 2; i++) {   // A tile: BM rows x 4 chunks
      int g = i * 256 + tid;
      int r = g >> 2, kc = g & 3;
      size_t ga = (size_t)(m0 + r) * K + k0 + kc * 8;
      async16(&Ah[ga], &Ash[g * 8]);
      async16(&Al[ga], &Asl[g * 8]);
    }
    #pragma unroll
    for (int i = 0; i < TN / 2; i++) {   // B tile: BN rows x 4 chunks
      int g = i * 256 + tid;
      int r = g >> 2, kc = g & 3;
      size_t gb = (size_t)(n0 + r) * K + k0 + kc * 8;
      async16(&Bh[gb], &Bsh[g * 8]);
      async16(&Bl[gb], &Bsl[g * 8]);
    }
    __syncthreads();  // drains vmcnt(0): all tiles landed

    short8 afh[MT], bfr[TN];
    #pragma unroll
    for (int t = 0; t < MT; t++)
      afh[t] = *(const short8*)&Ash[(wm + t * 16 + lrow) * 32 + lq * 8];
    #pragma unroll
    for (int t = 0; t < TN; t++)
      bfr[t] = *(const short8*)&Bsh[(wn + t * 16 + lrow) * 32 + lq * 8];
    #pragma unroll
    for (int ti = 0; ti < MT; ti++)
      #pragma unroll
      for (int tj = 0; tj < TN; tj++)
        acc[ti][tj] = __builtin_amdgcn_mfma_f32_16x16x32_bf16(afh[ti], bfr[tj], acc[ti][tj], 0, 0, 0);

    {
      short8 afl[MT];
      #pragma unroll
      for (int t = 0; t < MT; t++)
        afl[t] = *(const short8*)&Asl[(wm + t * 16 + lrow) * 32 + lq * 8];
      #pragma unroll
      for (int ti = 0; ti < MT; ti++)
        #pragma unroll
        for (int tj = 0; tj < TN; tj++)
          acc[ti][tj] = __builtin_amdgcn_mfma_f32_16x16x32_bf16(afl[ti], bfr[tj], acc[ti][tj], 0, 0, 0);
    }
    #pragma unroll
    for (int t = 0; t < TN; t++)
      bfr[t] = *(const short8*)&Bsl[(wn + t * 16 + lrow) * 32 + lq * 8];
    #pragma unroll
    for (int ti = 0; ti < MT; ti++)
      #pragma unroll
      for (int tj = 0; tj < TN; tj++)
        acc[ti][tj] = __builtin_amdgcn_mfma_f32_16x16x32_bf16(afh[ti], bfr[tj], acc[ti][tj], 0, 0, 0);
  }

  // epilogue
  #pragma unroll
  for (int ti = 0; ti < MT; ti++) {
    #pragma unroll
    for (int tj = 0; tj < TN; tj++) {
      int row0 = m0 + wm + ti * 16 + lq * 4;
      int col = n0 + wn + tj * 16 + lrow;
      #pragma unroll
      for (int r = 0; r < 4; r++) {
        int m = row0 + r;
        float fv = acc[ti][tj][r];
        if (EPI == 0) {
          size_t idx = (size_t)((m >> 10) * 8 + (col >> 6)) * 65536 + (m & 1023) * 64 + (col & 63);
          ushort_t h = f2bf(fv);
          o_hi[idx] = h;
          o_lo[idx] = f2bf(fv - bf2f(h));
        } else if (EPI == 1) {
          if (col < 512) {
            size_t idx = (size_t)((m >> 10) * 8 + (col >> 6)) * 65536 + (m & 1023) * 64 + (col & 63);
            ushort_t h = f2bf(fv);
            o_hi[idx] = h;
            o_lo[idx] = f2bf(fv - bf2f(h));
          } else {
            int cc = col - 512;
            o_vt[(size_t)(((m >> 10) * 8 + (cc >> 6)) * 64 + (cc & 63)) * 1024 + (m & 1023)] = f2bf(fv);
          }
        } else {
          outf[(size_t)m * ldo + col] = fv;   // fp32 final output
        }
      }
    }
  }
}

// ---------------- flash attention v4: swapped-operand, in-register softmax ----
// grid = 1024 blocks: bh = blk & 63 (so all q-tiles of one head share blk%8 ->
// same XCD -> K/V L2 reuse), qt = blk >> 6. 4 waves x 16 q-rows = 64 rows/block.
// QK^T computed as mfma(K,Q) -> S^T: each lane's scores have lane-local q (=lrow),
// softmax reduces via shfl_xor(16/32) over the 4 lq groups (no Sw LDS staging).
// PV computed as mfma(V^T,P) -> O^T: alpha/l scaling lane-local, no broadcasts.
// LDS 36,864 B -> 4 blocks/CU (16 waves/CU). K/V tile prefetched to regs before
// compute phase (latency hides under QK+softmax+PV).
__global__ __launch_bounds__(256, 4) void flash_attn(const ushort_t* __restrict__ qh,
                                                     const ushort_t* __restrict__ ql,
                                                     const ushort_t* __restrict__ kh,
                                                     const ushort_t* __restrict__ kl,
                                                     const ushort_t* __restrict__ vtb,
                                                     ushort_t* __restrict__ obh,
                                                     ushort_t* __restrict__ obl) {
  constexpr int KW = 36;   // K/V row stride (dwords): 4*(row) term spreads banks; b128-aligned
  constexpr int PWS = 36;  // Pw row stride (dwords)
  __shared__ __align__(16) unsigned Ksh[64 * KW];
  __shared__ __align__(16) unsigned Ksl[64 * KW];
  __shared__ __align__(16) unsigned VTs[64 * KW];
  __shared__ __align__(16) unsigned Pw[4][16 * PWS];  // per wave: P[q=lrow][k/2]

  const int tid = threadIdx.x;
  const int wave = tid >> 6, lane = tid & 63;
  const int bh = blockIdx.x & 63, qt = blockIdx.x >> 6;
  const int lrow = lane & 15, lq = lane >> 4;

  const ushort_t* Qh = qh + (size_t)bh * 65536;
  const ushort_t* Ql = ql + (size_t)bh * 65536;
  const ushort_t* Kph = kh + (size_t)bh * 65536;
  const ushort_t* Kpl = kl + (size_t)bh * 65536;
  const ushort_t* VT = vtb + (size_t)bh * 65536;

  const int qrow0 = qt * 64 + wave * 16;

  // Q fragments (B-operand layout: row=q=lrow, d-chunk = s*32+lq*8)
  short8 qfh[2], qfl[2];
  #pragma unroll
  for (int s = 0; s < 2; s++) {
    size_t idx = (size_t)(qrow0 + lrow) * 64 + s * 32 + lq * 8;
    qfh[s] = *(const short8*)&Qh[idx];
    qfl[s] = *(const short8*)&Ql[idx];
  }

  const f32x4 z = {0.f, 0.f, 0.f, 0.f};
  f32x4 oaccT[4];          // O^T: [dt]; row=d=dt*16+lq*4+e, col=q=lrow
  #pragma unroll
  for (int dt = 0; dt < 4; dt++) oaccT[dt] = z;

  float m_i = -1e30f, l_i = 0.f;   // lane-local: q = qrow0 + lrow

  // K/V tile prefetch registers
  short8 skh[2], skl[2], sv[2];
  #pragma unroll
  for (int i = 0; i < 2; i++) {
    int g = i * 256 + tid, rw = g >> 3, ch = g & 7;
    size_t kidx = (size_t)rw * 64 + ch * 8;
    skh[i] = *(const short8*)&Kph[kidx];
    skl[i] = *(const short8*)&Kpl[kidx];
    sv[i]  = *(const short8*)&VT[(size_t)rw * 1024 + ch * 8];
  }

  for (int kt = 0; kt < 16; kt++) {
    __syncthreads();   // prev iteration's LDS reads done
    #pragma unroll
    for (int i = 0; i < 2; i++) {
      int g = i * 256 + tid, rw = g >> 3, ch = g & 7;
      int lofs = rw * KW + ch * 4;
      *(uint4v*)&Ksh[lofs] = s8u4(skh[i]);
      *(uint4v*)&Ksl[lofs] = s8u4(skl[i]);
      *(uint4v*)&VTs[lofs] = s8u4(sv[i]);
    }
    __syncthreads();   // tiles visible to all waves

    // prefetch next tile into regs; latency hides under compute below
    if (kt < 15) {
      #pragma unroll
      for (int i = 0; i < 2; i++) {
        int g = i * 256 + tid, rw = g >> 3, ch = g & 7;
        size_t kidx = (size_t)((kt + 1) * 64 + rw) * 64 + ch * 8;
        skh[i] = *(const short8*)&Kph[kidx];
        skl[i] = *(const short8*)&Kpl[kidx];
        sv[i]  = *(const short8*)&VT[(size_t)rw * 1024 + (kt + 1) * 64 + ch * 8];
      }
    }

    // ---- QK^T swapped: sacc[nt] = S^T tile, row=k=nt*16+lq*4+e, col=q=lrow ----
    f32x4 sacc[4];
    #pragma unroll
    for (int nt = 0; nt < 4; nt++) sacc[nt] = z;
    #pragma unroll
    for (int s = 0; s < 2; s++) {
      short8 kf[4];
      #pragma unroll
      for (int nt = 0; nt < 4; nt++)
        kf[nt] = u4s8(*(const uint4v*)&Ksh[(nt * 16 + lrow) * KW + s * 16 + lq * 4]);
      #pragma unroll
      for (int nt = 0; nt < 4; nt++) {
        sacc[nt] = __builtin_amdgcn_mfma_f32_16x16x32_bf16(kf[nt], qfh[s], sacc[nt], 0, 0, 0);
        sacc[nt] = __builtin_amdgcn_mfma_f32_16x16x32_bf16(kf[nt], qfl[s], sacc[nt], 0, 0, 0);
      }
      #pragma unroll
      for (int nt = 0; nt < 4; nt++) {
        short8 kfl = u4s8(*(const uint4v*)&Ksl[(nt * 16 + lrow) * KW + s * 16 + lq * 4]);
        sacc[nt] = __builtin_amdgcn_mfma_f32_16x16x32_bf16(kfl, qfh[s], sacc[nt], 0, 0, 0);
      }
    }

    // ---- in-register online softmax (row q = lrow; reduce over 4 lq groups) ----
    float mx = sacc[0][0];
    #pragma unroll
    for (int nt = 0; nt < 4; nt++)
      #pragma unroll
      for (int e = 0; e < 4; e++) mx = fmaxf(mx, sacc[nt][e]);
    mx = fmaxf(mx, __shfl_xor(mx, 16));
    mx = fmaxf(mx, __shfl_xor(mx, 32));
    float mnew = fmaxf(m_i, mx);
    float mL = mnew * LOG2E;
    float alpha = exp2f(fmaf(m_i, LOG2E, -mL));
    float sum = 0.f;
    #pragma unroll
    for (int nt = 0; nt < 4; nt++) {
      f32x4 p;
      #pragma unroll
      for (int e = 0; e < 4; e++) {
        p[e] = exp2f(fmaf(sacc[nt][e], LOG2E, -mL));
        sum += p[e];
      }
      unsigned w0 = __builtin_amdgcn_perm(fu(p[1]), fu(p[0]), 0x07060302u);
      unsigned w1 = __builtin_amdgcn_perm(fu(p[3]), fu(p[2]), 0x07060302u);
      *(uint2v*)&Pw[wave][lrow * PWS + nt * 8 + lq * 2] = (uint2v){w0, w1};
    }
    sum += __shfl_xor(sum, 16);
    sum += __shfl_xor(sum, 32);
    l_i = fmaf(l_i, alpha, sum);
    m_i = mnew;
    #pragma unroll
    for (int dt = 0; dt < 4; dt++)
      #pragma unroll
      for (int e = 0; e < 4; e++) oaccT[dt][e] *= alpha;   // lane-local q rescale

    // ---- PV swapped: oaccT[dt] += V^T . P^T (A=V^T frag, B=P frag) ----
    #pragma unroll
    for (int s = 0; s < 2; s++) {
      short8 pf = u4s8(*(const uint4v*)&Pw[wave][lrow * PWS + s * 16 + lq * 4]);
      #pragma unroll
      for (int dt = 0; dt < 4; dt++) {
        short8 vf = u4s8(*(const uint4v*)&VTs[(dt * 16 + lrow) * KW + s * 16 + lq * 4]);
        oaccT[dt] = __builtin_amdgcn_mfma_f32_16x16x32_bf16(vf, pf, oaccT[dt], 0, 0, 0);
      }
    }
  }

  // ---- epilogue: lane-local 1/l, vectorized uint2 stores ----
  const int b = bh >> 3, h = bh & 7;
  const int n = qrow0 + lrow;
  float rinv = 1.f / l_i;
  #pragma unroll
  for (int dt = 0; dt < 4; dt++) {
    ushort_t hv[4], lv[4];
    #pragma unroll
    for (int e = 0; e < 4; e++) {
      float f = oaccT[dt][e] * rinv;
      hv[e] = f2bf(f);
      lv[e] = f2bf(f - bf2f(hv[e]));
    }
    size_t idx = (size_t)(b * 1024 + n) * 512 + h * 64 + dt * 16 + lq * 4;
    *(uint2v*)&obh[idx] = (uint2v){(unsigned)hv[0] | ((unsigned)hv[1] << 16),
                                   (unsigned)hv[2] | ((unsigned)hv[3] << 16)};
    *(uint2v*)&obl[idx] = (uint2v){(unsigned)lv[0] | ((unsigned)lv[1] << 16),
                                   (unsigned)lv[2] | ((unsigned)lv[3] << 16)};
  }
}

// ---------------- launcher ----------------
extern "C" void kernel_launch(void* const* d_in, const int* in_sizes, int n_in,
                              void* d_out, int out_size, void* d_ws, size_t ws_size,
                              hipStream_t stream) {
  const float* cur = (const float*)d_in[0];   // [8,1024,512] fp32
  const float* hid = (const float*)d_in[1];   // [8,1024,512] fp32
  const float* Wq  = (const float*)d_in[2];   // [512,512]
  const float* Wkv = (const float*)d_in[3];   // [512,1024]
  const float* Wo  = (const float*)d_in[4];   // [512,512]

  ushort_t* ws = (ushort_t*)d_ws;
  ushort_t* Ch = ws;                    // 4,194,304  (cur split; reused: aout hi)
  ushort_t* Cl = Ch + 4194304;          // 4,194,304  (cur split; reused: aout lo)
  ushort_t* Hh = Cl + 4194304;          // 4,194,304  (hid split)
  ushort_t* Hl = Hh + 4194304;          // 4,194,304
  ushort_t* kh = Hl + 4194304;          // 4,194,304
  ushort_t* kl = kh + 4194304;          // 4,194,304
  ushort_t* vt = kl + 4194304;          // 4,194,304
  ushort_t* qhb = vt + 4194304;         // 4,194,304
  ushort_t* qlb = qhb + 4194304;        // 4,194,304
  ushort_t* WqTh = qlb + 4194304;       // 262,144
  ushort_t* WqTl = WqTh + 262144;       // 262,144
  ushort_t* WkvTh = WqTl + 262144;      // 524,288
  ushort_t* WkvTl = WkvTh + 524288;     // 524,288
  ushort_t* WoTh = WkvTl + 524288;      // 262,144
  ushort_t* WoTl = WoTh + 262144;       // 262,144

  transpose_all<<<1024, 256, 0, stream>>>(Wq, Wkv, Wo, WqTh, WqTl, WkvTh, WkvTl, WoTh, WoTl);
  split_all<<<4096, 256, 0, stream>>>(cur, hid, Ch, Cl, Hh, Hl);

  // kv projection: BM=64, BN=128 -> grid (8,128) = 1024 blocks (4/CU)
  gemm3_bt<1, 2, 4><<<dim3(8, 128), 256, 0, stream>>>(Hh, Hl, WkvTh, WkvTl,
                                                      kh, kl, vt, (float*)nullptr, 512, 0);
  // q projection: BM=64, BN=128 -> grid (4,128) = 512 blocks (2/CU)
  gemm3_bt<0, 2, 4><<<dim3(4, 128), 256, 0, stream>>>(Ch, Cl, WqTh, WqTl,
                                                      qhb, qlb, (ushort_t*)nullptr, (float*)nullptr, 512, 0);
  // attention: 1024 blocks (bh-major XCD grouping), 64 q-rows/block
  flash_attn<<<1024, 256, 0, stream>>>(qhb, qlb, kh, kl, vt, Ch, Cl);
  // output projection: BM=64, BN=128 -> grid (4,128) = 512 blocks -> fp32 d_out
  gemm3_bt<2, 2, 4><<<dim3(4, 128), 256, 0, stream>>>(Ch, Cl, WoTh, WoTl,
                                                      (ushort_t*)nullptr, (ushort_t*)nullptr,
                                                      (ushort_t*)nullptr, (float*)d_out, 512, 512);
}

// Round 2
// 228.515 us; speedup vs baseline: 1.0985x; 1.0985x over previous
//
#include <hip/hip_runtime.h>

typedef unsigned short ushort_t;
typedef __attribute__((ext_vector_type(8))) short short8;
typedef __attribute__((ext_vector_type(4))) float f32x4;
typedef __attribute__((ext_vector_type(16))) float f32x16;
typedef __attribute__((ext_vector_type(2))) unsigned uint2v;
typedef __attribute__((ext_vector_type(4))) unsigned uint4v;

#define LOG2E 1.44269504088896f

// async global->LDS, 16B per lane. LDS dest must be wave-uniform base + lane*16.
__device__ __forceinline__ void async16(const void* g, void* l) {
  __builtin_amdgcn_global_load_lds(
      (const __attribute__((address_space(1))) void*)g,
      (__attribute__((address_space(3))) void*)l, 16, 0, 0);
}

__device__ __forceinline__ ushort_t f2bf(float f) {
  union { float f; unsigned u; } x; x.f = f;
  unsigned u = x.u;
  u += 0x7fffu + ((u >> 16) & 1u);
  return (ushort_t)(u >> 16);
}

__device__ __forceinline__ float bf2f(ushort_t w) {
  union { unsigned u; float f; } x; x.u = ((unsigned)w) << 16;
  return x.f;
}

__device__ __forceinline__ short8 u4s8(uint4v u) { union { uint4v a; short8 b; } c; c.a = u; return c.b; }
__device__ __forceinline__ uint4v s8u4(short8 s) { union { short8 a; uint4v b; } c; c.a = s; return c.b; }
__device__ __forceinline__ unsigned fu(float f) { union { float a; unsigned b; } c; c.a = f; return c.b; }

__device__ __forceinline__ f32x16 zero16() {
  f32x16 v;
  #pragma unroll
  for (int i = 0; i < 16; i++) v[i] = 0.f;
  return v;
}

// ------------- merged split ingest: cur+hid fp32 -> (hi, lo) bf16 -------------
__global__ __launch_bounds__(256) void split_all(const float* __restrict__ cur,
                                                 const float* __restrict__ hid,
                                                 ushort_t* __restrict__ ch,
                                                 ushort_t* __restrict__ cl,
                                                 ushort_t* __restrict__ hh,
                                                 ushort_t* __restrict__ hl) {
  int i = blockIdx.x * 256 + threadIdx.x;       // 0 .. 2*524288-1
  const float* src;
  ushort_t *hi, *lo;
  int j;
  if (i < 524288) { src = cur; hi = ch; lo = cl; j = i; }
  else            { src = hid; hi = hh; lo = hl; j = i - 524288; }
  const f32x4* s = (const f32x4*)src;
  f32x4 a = s[j * 2], b = s[j * 2 + 1];
  short8 oh, ol;
  #pragma unroll
  for (int k = 0; k < 4; k++) {
    ushort_t h = f2bf(a[k]); oh[k] = (short)h; ol[k] = (short)f2bf(a[k] - bf2f(h));
    h = f2bf(b[k]); oh[k + 4] = (short)h; ol[k + 4] = (short)f2bf(b[k] - bf2f(h));
  }
  ((short8*)hi)[j] = oh;
  ((short8*)lo)[j] = ol;
}

// ------- merged weight transpose+split: 3 matrices in one launch -------
__global__ __launch_bounds__(256) void transpose_all(const float* __restrict__ Wq,
                                                     const float* __restrict__ Wkv,
                                                     const float* __restrict__ Wo,
                                                     ushort_t* __restrict__ qh, ushort_t* __restrict__ ql,
                                                     ushort_t* __restrict__ kvh, ushort_t* __restrict__ kvl,
                                                     ushort_t* __restrict__ oh, ushort_t* __restrict__ ol) {
  __shared__ float tile[32][33];
  int bid = blockIdx.x;
  const float* src; ushort_t *dh, *dl; int Nn, bx, by;
  const int K = 512;
  if (bid < 256)      { src = Wq;  dh = qh;  dl = ql;  Nn = 512;  bx = (bid & 15) * 32; by = (bid >> 4) * 32; }
  else if (bid < 768) { int b = bid - 256; src = Wkv; dh = kvh; dl = kvl; Nn = 1024; bx = (b & 31) * 32; by = (b >> 5) * 32; }
  else                { int b = bid - 768; src = Wo;  dh = oh;  dl = ol;  Nn = 512;  bx = (b & 15) * 32; by = (b >> 4) * 32; }
  int tx = threadIdx.x & 31, ty = threadIdx.x >> 5;   // (32, 8)
  #pragma unroll
  for (int i = 0; i < 32; i += 8)
    tile[ty + i][tx] = src[(size_t)(by + ty + i) * Nn + bx + tx];
  __syncthreads();
  #pragma unroll
  for (int i = 0; i < 32; i += 8) {
    float v = tile[tx][ty + i];
    ushort_t h = f2bf(v);
    size_t idx = (size_t)(bx + ty + i) * K + by + tx;
    dh[idx] = h;
    dl[idx] = f2bf(v - bf2f(h));
  }
}

// ---- split GEMM: C = (Ah+Al)[M][K] @ (Bh+Bl)[Nn][K]^T, 3-product bf16x3 ----
// BM = MT*32, BN = TN*32. 4 waves (2x2); wave tile = (MT*16) x (TN*16).
// EPI 0: C -> (o_hi,o_lo) q-layout [B*H][N][D]
// EPI 1: col<512 -> (o_hi,o_lo) k-layout; col>=512 -> o_vt bf16 [B*H][D][N]
// EPI 2: outf fp32 row-major [M][ldo]  (final output)
template<int EPI, int MT, int TN>
__global__ __launch_bounds__(256) void gemm3_bt(const ushort_t* __restrict__ Ah,
                                                const ushort_t* __restrict__ Al,
                                                const ushort_t* __restrict__ Bh,
                                                const ushort_t* __restrict__ Bl,
                                                ushort_t* __restrict__ o_hi,
                                                ushort_t* __restrict__ o_lo,
                                                ushort_t* __restrict__ o_vt,
                                                float* __restrict__ outf,
                                                int K, int ldo) {
  constexpr int BM = MT * 32;
  constexpr int BN = TN * 32;
  __shared__ __align__(16) ushort_t Ash[BM * 32];
  __shared__ __align__(16) ushort_t Asl[BM * 32];
  __shared__ __align__(16) ushort_t Bsh[BN * 32];
  __shared__ __align__(16) ushort_t Bsl[BN * 32];
  const int tid = threadIdx.x;
  const int wave = tid >> 6, lane = tid & 63;
  const int wm = (wave >> 1) * (MT * 16), wn = (wave & 1) * (TN * 16);
  const int m0 = blockIdx.y * BM, n0 = blockIdx.x * BN;
  const int lrow = lane & 15, lq = lane >> 4;

  f32x4 acc[MT][TN];
  const f32x4 z = {0.f, 0.f, 0.f, 0.f};
  #pragma unroll
  for (int i = 0; i < MT; i++)
    #pragma unroll
    for (int j = 0; j < TN; j++) acc[i][j] = z;

  for (int k0 = 0; k0 < K; k0 += 32) {
    __syncthreads();
    #pragma unroll
    for (int i = 0; i < MT / 2; i++) {   // A tile: BM rows x 4 chunks
      int g = i * 256 + tid;
      int r = g >> 2, kc = g & 3;
      size_t ga = (size_t)(m0 + r) * K + k0 + kc * 8;
      async16(&Ah[ga], &Ash[g * 8]);
      async16(&Al[ga], &Asl[g * 8]);
    }
    #pragma unroll
    for (int i = 0; i < TN / 2; i++) {   // B tile: BN rows x 4 chunks
      int g = i * 256 + tid;
      int r = g >> 2, kc = g & 3;
      size_t gb = (size_t)(n0 + r) * K + k0 + kc * 8;
      async16(&Bh[gb], &Bsh[g * 8]);
      async16(&Bl[gb], &Bsl[g * 8]);
    }
    __syncthreads();  // drains vmcnt(0): all tiles landed

    short8 afh[MT], bfr[TN];
    #pragma unroll
    for (int t = 0; t < MT; t++)
      afh[t] = *(const short8*)&Ash[(wm + t * 16 + lrow) * 32 + lq * 8];
    #pragma unroll
    for (int t = 0; t < TN; t++)
      bfr[t] = *(const short8*)&Bsh[(wn + t * 16 + lrow) * 32 + lq * 8];
    #pragma unroll
    for (int ti = 0; ti < MT; ti++)
      #pragma unroll
      for (int tj = 0; tj < TN; tj++)
        acc[ti][tj] = __builtin_amdgcn_mfma_f32_16x16x32_bf16(afh[ti], bfr[tj], acc[ti][tj], 0, 0, 0);

    {
      short8 afl[MT];
      #pragma unroll
      for (int t = 0; t < MT; t++)
        afl[t] = *(const short8*)&Asl[(wm + t * 16 + lrow) * 32 + lq * 8];
      #pragma unroll
      for (int ti = 0; ti < MT; ti++)
        #pragma unroll
        for (int tj = 0; tj < TN; tj++)
          acc[ti][tj] = __builtin_amdgcn_mfma_f32_16x16x32_bf16(afl[ti], bfr[tj], acc[ti][tj], 0, 0, 0);
    }
    #pragma unroll
    for (int t = 0; t < TN; t++)
      bfr[t] = *(const short8*)&Bsl[(wn + t * 16 + lrow) * 32 + lq * 8];
    #pragma unroll
    for (int ti = 0; ti < MT; ti++)
      #pragma unroll
      for (int tj = 0; tj < TN; tj++)
        acc[ti][tj] = __builtin_amdgcn_mfma_f32_16x16x32_bf16(afh[ti], bfr[tj], acc[ti][tj], 0, 0, 0);
  }

  // epilogue
  #pragma unroll
  for (int ti = 0; ti < MT; ti++) {
    #pragma unroll
    for (int tj = 0; tj < TN; tj++) {
      int row0 = m0 + wm + ti * 16 + lq * 4;
      int col = n0 + wn + tj * 16 + lrow;
      #pragma unroll
      for (int r = 0; r < 4; r++) {
        int m = row0 + r;
        float fv = acc[ti][tj][r];
        if (EPI == 0) {
          size_t idx = (size_t)((m >> 10) * 8 + (col >> 6)) * 65536 + (m & 1023) * 64 + (col & 63);
          ushort_t h = f2bf(fv);
          o_hi[idx] = h;
          o_lo[idx] = f2bf(fv - bf2f(h));
        } else if (EPI == 1) {
          if (col < 512) {
            size_t idx = (size_t)((m >> 10) * 8 + (col >> 6)) * 65536 + (m & 1023) * 64 + (col & 63);
            ushort_t h = f2bf(fv);
            o_hi[idx] = h;
            o_lo[idx] = f2bf(fv - bf2f(h));
          } else {
            int cc = col - 512;
            o_vt[(size_t)(((m >> 10) * 8 + (cc >> 6)) * 64 + (cc & 63)) * 1024 + (m & 1023)] = f2bf(fv);
          }
        } else {
          outf[(size_t)m * ldo + col] = fv;   // fp32 final output
        }
      }
    }
  }
}

// ---------------- flash attention v5: 32x32 MFMA core ----------------
// 512 blocks: bh = blk & 63 (head-major -> XCD L2 reuse), qt = blk >> 6 (8).
// 4 waves x 32 q-rows = 128 q-rows/block. QK^T swapped: sacc = mfma32(K, Q)
// = S^T (col = q = lane&31, row = k). Softmax in-register, one shfl_xor(32).
// P -> bf16 via v_cvt_pk_bf16_f32, redistributed to PV B-fragment with
// permlane32_swap (zero LDS for P). PV swapped: oacc = mfma32(V^T, P) = O^T.
// K/V staged via global_load_lds with pre-swizzled source (chunk ^= row&7,
// involution; read side applies same XOR) -> conflict-free b128 reads.
// Double-buffered LDS (48KB), one barrier per kt; DMA issued before compute,
// drained by the end-of-kt barrier (latency hidden under ~2000cyc compute).
__global__ __launch_bounds__(256, 2) void flash_attn(const ushort_t* __restrict__ qh,
                                                     const ushort_t* __restrict__ ql,
                                                     const ushort_t* __restrict__ kh,
                                                     const ushort_t* __restrict__ kl,
                                                     const ushort_t* __restrict__ vtb,
                                                     ushort_t* __restrict__ obh,
                                                     ushort_t* __restrict__ obl) {
  __shared__ __align__(16) ushort_t Ksh[2][64 * 64];
  __shared__ __align__(16) ushort_t Ksl[2][64 * 64];
  __shared__ __align__(16) ushort_t VTs[2][64 * 64];

  const int tid = threadIdx.x;
  const int wave = tid >> 6, lane = tid & 63;
  const int bh = blockIdx.x & 63, qt = blockIdx.x >> 6;
  const int l31 = lane & 31, hi = lane >> 5;

  const ushort_t* Qh = qh + (size_t)bh * 65536;
  const ushort_t* Ql = ql + (size_t)bh * 65536;
  const ushort_t* Kph = kh + (size_t)bh * 65536;
  const ushort_t* Kpl = kl + (size_t)bh * 65536;
  const ushort_t* VT = vtb + (size_t)bh * 65536;

  const int qrow0 = qt * 128 + wave * 32;

  // Q fragments (B-operand: col q = l31, contraction d = ds*16 + hi*8 + 0..7)
  short8 qfh[4], qfl[4];
  #pragma unroll
  for (int ds = 0; ds < 4; ds++) {
    size_t idx = (size_t)(qrow0 + l31) * 64 + ds * 16 + hi * 8;
    qfh[ds] = *(const short8*)&Qh[idx];
    qfl[ds] = *(const short8*)&Ql[idx];
  }

  f32x16 oacc[2];                 // O^T: [dtile]; row d, col q = l31
  oacc[0] = zero16();
  oacc[1] = zero16();
  float m_i = -1e30f, l_i = 0.f;  // per q = qrow0 + l31 (replicated over hi)

  // swizzled-read offsets: phys chunk = (2*i + hi) ^ (l31 & 7); i = ds or ks
  const int r7 = l31 & 7;
  int pc[4];
  #pragma unroll
  for (int i = 0; i < 4; i++) pc[i] = (((2 * i + hi) ^ r7) << 3);
  const int ro0 = l31 * 64, ro1 = ro0 + 2048;   // rows l31 and 32+l31

  // stage kt-tile into buffer d: linear LDS dest, inverse-swizzled global src
  auto stage = [&](int kt, int d) {
    #pragma unroll
    for (int i = 0; i < 2; i++) {
      int g = i * 256 + tid, rw = g >> 3, ch = g & 7;
      int co = ((ch ^ (rw & 7)) << 3);           // swizzled source column
      int lofs = rw * 64 + (ch << 3);            // linear LDS offset
      size_t kidx = (size_t)(kt * 64 + rw) * 64 + co;
      async16(&Kph[kidx], &Ksh[d][lofs]);
      async16(&Kpl[kidx], &Ksl[d][lofs]);
      async16(&VT[(size_t)rw * 1024 + kt * 64 + co], &VTs[d][lofs]);
    }
  };

  stage(0, 0);
  __syncthreads();   // drain: buf0 ready

  for (int kt = 0; kt < 16; kt++) {
    const int cur = kt & 1;
    if (kt < 15) stage(kt + 1, cur ^ 1);   // in-flight during compute

    // ---- QK^T: sacc[T] = S^T tile (rows k=32T.., cols q) , 3 rails ----
    f32x16 sacc0 = zero16(), sacc1 = zero16();
    #pragma unroll
    for (int ds = 0; ds < 4; ds++) {
      short8 kh0 = *(const short8*)&Ksh[cur][ro0 + pc[ds]];
      short8 kh1 = *(const short8*)&Ksh[cur][ro1 + pc[ds]];
      sacc0 = __builtin_amdgcn_mfma_f32_32x32x16_bf16(kh0, qfh[ds], sacc0, 0, 0, 0);
      sacc1 = __builtin_amdgcn_mfma_f32_32x32x16_bf16(kh1, qfh[ds], sacc1, 0, 0, 0);
      sacc0 = __builtin_amdgcn_mfma_f32_32x32x16_bf16(kh0, qfl[ds], sacc0, 0, 0, 0);
      sacc1 = __builtin_amdgcn_mfma_f32_32x32x16_bf16(kh1, qfl[ds], sacc1, 0, 0, 0);
      short8 kl0 = *(const short8*)&Ksl[cur][ro0 + pc[ds]];
      short8 kl1 = *(const short8*)&Ksl[cur][ro1 + pc[ds]];
      sacc0 = __builtin_amdgcn_mfma_f32_32x32x16_bf16(kl0, qfh[ds], sacc0, 0, 0, 0);
      sacc1 = __builtin_amdgcn_mfma_f32_32x32x16_bf16(kl1, qfh[ds], sacc1, 0, 0, 0);
    }

    // ---- in-register online softmax (q = l31; reduce across hi-halves) ----
    float mx = -1e30f;
    #pragma unroll
    for (int r = 0; r < 16; r++) {
      mx = fmaxf(mx, sacc0[r]);
      mx = fmaxf(mx, sacc1[r]);
    }
    mx = fmaxf(mx, __shfl_xor(mx, 32));
    float mnew = fmaxf(m_i, mx);
    float mL = mnew * LOG2E;
    float alpha = exp2f(fmaf(m_i, LOG2E, -mL));
    float sum = 0.f;
    unsigned pw[16];
    #pragma unroll
    for (int j = 0; j < 8; j++) {
      float p0 = exp2f(fmaf(sacc0[2 * j], LOG2E, -mL));
      float p1 = exp2f(fmaf(sacc0[2 * j + 1], LOG2E, -mL));
      sum += p0 + p1;
      asm("v_cvt_pk_bf16_f32 %0, %1, %2" : "=v"(pw[j]) : "v"(p0), "v"(p1));
    }
    #pragma unroll
    for (int j = 0; j < 8; j++) {
      float p0 = exp2f(fmaf(sacc1[2 * j], LOG2E, -mL));
      float p1 = exp2f(fmaf(sacc1[2 * j + 1], LOG2E, -mL));
      sum += p0 + p1;
      asm("v_cvt_pk_bf16_f32 %0, %1, %2" : "=v"(pw[8 + j]) : "v"(p0), "v"(p1));
    }
    sum += __shfl_xor(sum, 32);
    l_i = fmaf(l_i, alpha, sum);
    m_i = mnew;
    #pragma unroll
    for (int r = 0; r < 16; r++) {
      oacc[0][r] *= alpha;
      oacc[1][r] *= alpha;
    }

    // ---- PV: oacc[dt] += mfma32(V^T-frag, P-frag) ----
    // P-frag per ks via permlane32_swap: lanes<32 need k-block 16ks..+7,
    // lanes>=32 need 16ks+8..+15; own acc has the 4*hi half of each.
    #pragma unroll
    for (int ks = 0; ks < 4; ks++) {
      const int base = (ks >> 1) * 8 + (ks & 1) * 4;
      uint2v s0 = __builtin_amdgcn_permlane32_swap(pw[base + 0], pw[base + 2], false, false);
      uint2v s1 = __builtin_amdgcn_permlane32_swap(pw[base + 1], pw[base + 3], false, false);
      short8 pfrag = u4s8((uint4v){s0.x, s1.x, s0.y, s1.y});
      short8 vf0 = *(const short8*)&VTs[cur][ro0 + pc[ks]];
      short8 vf1 = *(const short8*)&VTs[cur][ro1 + pc[ks]];
      oacc[0] = __builtin_amdgcn_mfma_f32_32x32x16_bf16(vf0, pfrag, oacc[0], 0, 0, 0);
      oacc[1] = __builtin_amdgcn_mfma_f32_32x32x16_bf16(vf1, pfrag, oacc[1], 0, 0, 0);
    }

    if (kt < 15) __syncthreads();   // drains next-tile DMA + releases cur buf
  }

  // ---- epilogue: lane-local 1/l, uint2 stores ----
  const int b = bh >> 3, h = bh & 7;
  const int n = qrow0 + l31;
  float rinv = 1.f / l_i;
  #pragma unroll
  for (int dt = 0; dt < 2; dt++) {
    #pragma unroll
    for (int t = 0; t < 4; t++) {
      ushort_t hv[4], lv[4];
      #pragma unroll
      for (int e = 0; e < 4; e++) {
        float x = oacc[dt][4 * t + e] * rinv;
        hv[e] = f2bf(x);
        lv[e] = f2bf(x - bf2f(hv[e]));
      }
      size_t idx = (size_t)(b * 1024 + n) * 512 + h * 64 + dt * 32 + t * 8 + hi * 4;
      *(uint2v*)&obh[idx] = (uint2v){(unsigned)hv[0] | ((unsigned)hv[1] << 16),
                                     (unsigned)hv[2] | ((unsigned)hv[3] << 16)};
      *(uint2v*)&obl[idx] = (uint2v){(unsigned)lv[0] | ((unsigned)lv[1] << 16),
                                     (unsigned)lv[2] | ((unsigned)lv[3] << 16)};
    }
  }
}

// ---------------- launcher ----------------
extern "C" void kernel_launch(void* const* d_in, const int* in_sizes, int n_in,
                              void* d_out, int out_size, void* d_ws, size_t ws_size,
                              hipStream_t stream) {
  const float* cur = (const float*)d_in[0];   // [8,1024,512] fp32
  const float* hid = (const float*)d_in[1];   // [8,1024,512] fp32
  const float* Wq  = (const float*)d_in[2];   // [512,512]
  const float* Wkv = (const float*)d_in[3];   // [512,1024]
  const float* Wo  = (const float*)d_in[4];   // [512,512]

  ushort_t* ws = (ushort_t*)d_ws;
  ushort_t* Ch = ws;                    // 4,194,304  (cur split; reused: aout hi)
  ushort_t* Cl = Ch + 4194304;          // 4,194,304  (cur split; reused: aout lo)
  ushort_t* Hh = Cl + 4194304;          // 4,194,304  (hid split)
  ushort_t* Hl = Hh + 4194304;          // 4,194,304
  ushort_t* kh = Hl + 4194304;          // 4,194,304
  ushort_t* kl = kh + 4194304;          // 4,194,304
  ushort_t* vt = kl + 4194304;          // 4,194,304
  ushort_t* qhb = vt + 4194304;         // 4,194,304
  ushort_t* qlb = qhb + 4194304;        // 4,194,304
  ushort_t* WqTh = qlb + 4194304;       // 262,144
  ushort_t* WqTl = WqTh + 262144;       // 262,144
  ushort_t* WkvTh = WqTl + 262144;      // 524,288
  ushort_t* WkvTl = WkvTh + 524288;     // 524,288
  ushort_t* WoTh = WkvTl + 524288;      // 262,144
  ushort_t* WoTl = WoTh + 262144;       // 262,144

  transpose_all<<<1024, 256, 0, stream>>>(Wq, Wkv, Wo, WqTh, WqTl, WkvTh, WkvTl, WoTh, WoTl);
  split_all<<<4096, 256, 0, stream>>>(cur, hid, Ch, Cl, Hh, Hl);

  // kv projection: BM=64, BN=128 -> grid (8,128) = 1024 blocks (4/CU)
  gemm3_bt<1, 2, 4><<<dim3(8, 128), 256, 0, stream>>>(Hh, Hl, WkvTh, WkvTl,
                                                      kh, kl, vt, (float*)nullptr, 512, 0);
  // q projection: BM=64, BN=128 -> grid (4,128) = 512 blocks (2/CU)
  gemm3_bt<0, 2, 4><<<dim3(4, 128), 256, 0, stream>>>(Ch, Cl, WqTh, WqTl,
                                                      qhb, qlb, (ushort_t*)nullptr, (float*)nullptr, 512, 0);
  // attention: 512 blocks (head-major XCD grouping), 128 q-rows/block
  flash_attn<<<512, 256, 0, stream>>>(qhb, qlb, kh, kl, vt, Ch, Cl);
  // output projection: BM=64, BN=128 -> grid (4,128) = 512 blocks -> fp32 d_out
  gemm3_bt<2, 2, 4><<<dim3(4, 128), 256, 0, stream>>>(Ch, Cl, WoTh, WoTl,
                                                      (ushort_t*)nullptr, (ushort_t*)nullptr,
                                                      (ushort_t*)nullptr, (float*)d_out, 512, 512);
}

// Round 4
// 226.625 us; speedup vs baseline: 1.1077x; 1.0083x over previous
//
#include <hip/hip_runtime.h>

typedef unsigned short ushort_t;
typedef __attribute__((ext_vector_type(8))) short short8;
typedef __attribute__((ext_vector_type(4))) float f32x4;
typedef __attribute__((ext_vector_type(16))) float f32x16;
typedef __attribute__((ext_vector_type(2))) unsigned uint2v;
typedef __attribute__((ext_vector_type(4))) unsigned uint4v;

#define LOG2E 1.44269504088896f

// async global->LDS, 16B per lane. LDS dest must be wave-uniform base + lane*16.
__device__ __forceinline__ void async16(const void* g, void* l) {
  __builtin_amdgcn_global_load_lds(
      (const __attribute__((address_space(1))) void*)g,
      (__attribute__((address_space(3))) void*)l, 16, 0, 0);
}

__device__ __forceinline__ ushort_t f2bf(float f) {
  union { float f; unsigned u; } x; x.f = f;
  unsigned u = x.u;
  u += 0x7fffu + ((u >> 16) & 1u);
  return (ushort_t)(u >> 16);
}

__device__ __forceinline__ float bf2f(ushort_t w) {
  union { unsigned u; float f; } x; x.u = ((unsigned)w) << 16;
  return x.f;
}

__device__ __forceinline__ short8 u4s8(uint4v u) { union { uint4v a; short8 b; } c; c.a = u; return c.b; }
__device__ __forceinline__ uint4v s8u4(short8 s) { union { short8 a; uint4v b; } c; c.a = s; return c.b; }
__device__ __forceinline__ unsigned fu(float f) { union { float a; unsigned b; } c; c.a = f; return c.b; }

__device__ __forceinline__ f32x16 zero16() {
  f32x16 v;
  #pragma unroll
  for (int i = 0; i < 16; i++) v[i] = 0.f;
  return v;
}

// ------------- merged ingest: weight transpose+split AND activation split ----
// blocks 0..1023: transpose+split Wq/Wkv/Wo (as before)
// blocks 1024..5119: split cur/hid fp32 -> (hi, lo) bf16
__global__ __launch_bounds__(256) void prep_all(const float* __restrict__ cur,
                                                const float* __restrict__ hid,
                                                const float* __restrict__ Wq,
                                                const float* __restrict__ Wkv,
                                                const float* __restrict__ Wo,
                                                ushort_t* __restrict__ ch, ushort_t* __restrict__ cl,
                                                ushort_t* __restrict__ hh, ushort_t* __restrict__ hl,
                                                ushort_t* __restrict__ qh, ushort_t* __restrict__ ql,
                                                ushort_t* __restrict__ kvh, ushort_t* __restrict__ kvl,
                                                ushort_t* __restrict__ oh, ushort_t* __restrict__ ol) {
  __shared__ float tile[32][33];
  int bid = blockIdx.x;
  if (bid >= 1024) {
    // ---- activation split path ----
    int i = (bid - 1024) * 256 + threadIdx.x;       // 0 .. 2*524288-1
    const float* src;
    ushort_t *hi, *lo;
    int j;
    if (i < 524288) { src = cur; hi = ch; lo = cl; j = i; }
    else            { src = hid; hi = hh; lo = hl; j = i - 524288; }
    const f32x4* s = (const f32x4*)src;
    f32x4 a = s[j * 2], b = s[j * 2 + 1];
    short8 ohh, oll;
    #pragma unroll
    for (int k = 0; k < 4; k++) {
      ushort_t h = f2bf(a[k]); ohh[k] = (short)h; oll[k] = (short)f2bf(a[k] - bf2f(h));
      h = f2bf(b[k]); ohh[k + 4] = (short)h; oll[k + 4] = (short)f2bf(b[k] - bf2f(h));
    }
    ((short8*)hi)[j] = ohh;
    ((short8*)lo)[j] = oll;
    return;
  }
  // ---- weight transpose+split path ----
  const float* src; ushort_t *dh, *dl; int Nn, bx, by;
  const int K = 512;
  if (bid < 256)      { src = Wq;  dh = qh;  dl = ql;  Nn = 512;  bx = (bid & 15) * 32; by = (bid >> 4) * 32; }
  else if (bid < 768) { int b = bid - 256; src = Wkv; dh = kvh; dl = kvl; Nn = 1024; bx = (b & 31) * 32; by = (b >> 5) * 32; }
  else                { int b = bid - 768; src = Wo;  dh = oh;  dl = ol;  Nn = 512;  bx = (b & 15) * 32; by = (b >> 4) * 32; }
  int tx = threadIdx.x & 31, ty = threadIdx.x >> 5;   // (32, 8)
  #pragma unroll
  for (int i = 0; i < 32; i += 8)
    tile[ty + i][tx] = src[(size_t)(by + ty + i) * Nn + bx + tx];
  __syncthreads();
  #pragma unroll
  for (int i = 0; i < 32; i += 8) {
    float v = tile[tx][ty + i];
    ushort_t h = f2bf(v);
    size_t idx = (size_t)(bx + ty + i) * K + by + tx;
    dh[idx] = h;
    dl[idx] = f2bf(v - bf2f(h));
  }
}

// ---- split GEMM: C = (Ah+Al)[M][K] @ (Bh+Bl)[Nn][K]^T, 3-product bf16x3 ----
// T3 2-phase: double-buffered LDS; DMA for step k+1 issued at top of step k
// (covered by the whole compute phase); ONE barrier per K-step.
template<int EPI, int MT, int TN>
__global__ __launch_bounds__(256) void gemm3_bt(const ushort_t* __restrict__ Ah,
                                                const ushort_t* __restrict__ Al,
                                                const ushort_t* __restrict__ Bh,
                                                const ushort_t* __restrict__ Bl,
                                                ushort_t* __restrict__ o_hi,
                                                ushort_t* __restrict__ o_lo,
                                                ushort_t* __restrict__ o_vt,
                                                float* __restrict__ outf,
                                                int K, int ldo) {
  constexpr int BM = MT * 32;
  constexpr int BN = TN * 32;
  __shared__ __align__(16) ushort_t Ash[2][BM * 32];
  __shared__ __align__(16) ushort_t Asl[2][BM * 32];
  __shared__ __align__(16) ushort_t Bsh[2][BN * 32];
  __shared__ __align__(16) ushort_t Bsl[2][BN * 32];
  const int tid = threadIdx.x;
  const int wave = tid >> 6, lane = tid & 63;
  const int wm = (wave >> 1) * (MT * 16), wn = (wave & 1) * (TN * 16);
  const int m0 = blockIdx.y * BM, n0 = blockIdx.x * BN;
  const int lrow = lane & 15, lq = lane >> 4;

  f32x4 acc[MT][TN];
  const f32x4 z = {0.f, 0.f, 0.f, 0.f};
  #pragma unroll
  for (int i = 0; i < MT; i++)
    #pragma unroll
    for (int j = 0; j < TN; j++) acc[i][j] = z;

  auto stage = [&](int k0, int d) {
    #pragma unroll
    for (int i = 0; i < MT / 2; i++) {   // A tile: BM rows x 4 chunks
      int g = i * 256 + tid;
      int r = g >> 2, kc = g & 3;
      size_t ga = (size_t)(m0 + r) * K + k0 + kc * 8;
      async16(&Ah[ga], &Ash[d][g * 8]);
      async16(&Al[ga], &Asl[d][g * 8]);
    }
    #pragma unroll
    for (int i = 0; i < TN / 2; i++) {   // B tile: BN rows x 4 chunks
      int g = i * 256 + tid;
      int r = g >> 2, kc = g & 3;
      size_t gb = (size_t)(n0 + r) * K + k0 + kc * 8;
      async16(&Bh[gb], &Bsh[d][g * 8]);
      async16(&Bl[gb], &Bsl[d][g * 8]);
    }
  };

  stage(0, 0);
  __syncthreads();   // buf0 landed

  int cur = 0;
  for (int k0 = 0; k0 < K; k0 += 32) {
    if (k0 + 32 < K) stage(k0 + 32, cur ^ 1);   // in flight during compute

    short8 afh[MT], bfr[TN];
    #pragma unroll
    for (int t = 0; t < MT; t++)
      afh[t] = *(const short8*)&Ash[cur][(wm + t * 16 + lrow) * 32 + lq * 8];
    #pragma unroll
    for (int t = 0; t < TN; t++)
      bfr[t] = *(const short8*)&Bsh[cur][(wn + t * 16 + lrow) * 32 + lq * 8];
    #pragma unroll
    for (int ti = 0; ti < MT; ti++)
      #pragma unroll
      for (int tj = 0; tj < TN; tj++)
        acc[ti][tj] = __builtin_amdgcn_mfma_f32_16x16x32_bf16(afh[ti], bfr[tj], acc[ti][tj], 0, 0, 0);

    {
      short8 afl[MT];
      #pragma unroll
      for (int t = 0; t < MT; t++)
        afl[t] = *(const short8*)&Asl[cur][(wm + t * 16 + lrow) * 32 + lq * 8];
      #pragma unroll
      for (int ti = 0; ti < MT; ti++)
        #pragma unroll
        for (int tj = 0; tj < TN; tj++)
          acc[ti][tj] = __builtin_amdgcn_mfma_f32_16x16x32_bf16(afl[ti], bfr[tj], acc[ti][tj], 0, 0, 0);
    }
    #pragma unroll
    for (int t = 0; t < TN; t++)
      bfr[t] = *(const short8*)&Bsl[cur][(wn + t * 16 + lrow) * 32 + lq * 8];
    #pragma unroll
    for (int ti = 0; ti < MT; ti++)
      #pragma unroll
      for (int tj = 0; tj < TN; tj++)
        acc[ti][tj] = __builtin_amdgcn_mfma_f32_16x16x32_bf16(afh[ti], bfr[tj], acc[ti][tj], 0, 0, 0);

    __syncthreads();   // drains next-tile DMA + releases cur buffer
    cur ^= 1;
  }

  // epilogue
  #pragma unroll
  for (int ti = 0; ti < MT; ti++) {
    #pragma unroll
    for (int tj = 0; tj < TN; tj++) {
      int row0 = m0 + wm + ti * 16 + lq * 4;
      int col = n0 + wn + tj * 16 + lrow;
      #pragma unroll
      for (int r = 0; r < 4; r++) {
        int m = row0 + r;
        float fv = acc[ti][tj][r];
        if (EPI == 0) {
          size_t idx = (size_t)((m >> 10) * 8 + (col >> 6)) * 65536 + (m & 1023) * 64 + (col & 63);
          ushort_t h = f2bf(fv);
          o_hi[idx] = h;
          o_lo[idx] = f2bf(fv - bf2f(h));
        } else if (EPI == 1) {
          if (col < 512) {
            size_t idx = (size_t)((m >> 10) * 8 + (col >> 6)) * 65536 + (m & 1023) * 64 + (col & 63);
            ushort_t h = f2bf(fv);
            o_hi[idx] = h;
            o_lo[idx] = f2bf(fv - bf2f(h));
          } else {
            int cc = col - 512;
            o_vt[(size_t)(((m >> 10) * 8 + (cc >> 6)) * 64 + (cc & 63)) * 1024 + (m & 1023)] = f2bf(fv);
          }
        } else {
          outf[(size_t)m * ldo + col] = fv;   // fp32 final output
        }
      }
    }
  }
}

// ---------------- flash attention v5 (round-2 proven) + s_setprio ----------
// 512 blocks: bh = blk & 63 (head-major -> XCD L2 reuse), qt = blk >> 6 (8).
// 4 waves x 32 q-rows = 128 q-rows/block. QK^T swapped: sacc = mfma32(K, Q)
// = S^T (col = q = lane&31, row = k). Softmax in-register, one shfl_xor(32).
// P -> bf16 via v_cvt_pk_bf16_f32, redistributed to PV B-fragment with
// permlane32_swap (zero LDS for P). PV swapped: oacc = mfma32(V^T, P) = O^T.
// K/V staged via global_load_lds with pre-swizzled source (chunk ^= row&7,
// involution; read side applies same XOR) -> conflict-free b128 reads.
// Double-buffered LDS (48KB), one barrier per kt.
__global__ __launch_bounds__(256, 2) void flash_attn(const ushort_t* __restrict__ qh,
                                                     const ushort_t* __restrict__ ql,
                                                     const ushort_t* __restrict__ kh,
                                                     const ushort_t* __restrict__ kl,
                                                     const ushort_t* __restrict__ vtb,
                                                     ushort_t* __restrict__ obh,
                                                     ushort_t* __restrict__ obl) {
  __shared__ __align__(16) ushort_t Ksh[2][64 * 64];
  __shared__ __align__(16) ushort_t Ksl[2][64 * 64];
  __shared__ __align__(16) ushort_t VTs[2][64 * 64];

  const int tid = threadIdx.x;
  const int wave = tid >> 6, lane = tid & 63;
  const int bh = blockIdx.x & 63, qt = blockIdx.x >> 6;
  const int l31 = lane & 31, hi = lane >> 5;

  const ushort_t* Qh = qh + (size_t)bh * 65536;
  const ushort_t* Ql = ql + (size_t)bh * 65536;
  const ushort_t* Kph = kh + (size_t)bh * 65536;
  const ushort_t* Kpl = kl + (size_t)bh * 65536;
  const ushort_t* VT = vtb + (size_t)bh * 65536;

  const int qrow0 = qt * 128 + wave * 32;

  // Q fragments (B-operand: col q = l31, contraction d = ds*16 + hi*8 + 0..7)
  short8 qfh[4], qfl[4];
  #pragma unroll
  for (int ds = 0; ds < 4; ds++) {
    size_t idx = (size_t)(qrow0 + l31) * 64 + ds * 16 + hi * 8;
    qfh[ds] = *(const short8*)&Qh[idx];
    qfl[ds] = *(const short8*)&Ql[idx];
  }

  f32x16 oacc[2];                 // O^T: [dtile]; row d, col q = l31
  oacc[0] = zero16();
  oacc[1] = zero16();
  float m_i = -1e30f, l_i = 0.f;  // per q = qrow0 + l31 (replicated over hi)

  // swizzled-read offsets: phys chunk = (2*i + hi) ^ (l31 & 7); i = ds or ks
  const int r7 = l31 & 7;
  int pc[4];
  #pragma unroll
  for (int i = 0; i < 4; i++) pc[i] = (((2 * i + hi) ^ r7) << 3);
  const int ro0 = l31 * 64, ro1 = ro0 + 2048;   // rows l31 and 32+l31

  // stage kt-tile into buffer d: linear LDS dest, inverse-swizzled global src
  auto stage = [&](int kt, int d) {
    #pragma unroll
    for (int i = 0; i < 2; i++) {
      int g = i * 256 + tid, rw = g >> 3, ch = g & 7;
      int co = ((ch ^ (rw & 7)) << 3);           // swizzled source column
      int lofs = rw * 64 + (ch << 3);            // linear LDS offset
      size_t kidx = (size_t)(kt * 64 + rw) * 64 + co;
      async16(&Kph[kidx], &Ksh[d][lofs]);
      async16(&Kpl[kidx], &Ksl[d][lofs]);
      async16(&VT[(size_t)rw * 1024 + kt * 64 + co], &VTs[d][lofs]);
    }
  };

  stage(0, 0);
  __syncthreads();   // drain: buf0 ready

  for (int kt = 0; kt < 16; kt++) {
    const int cur = kt & 1;
    if (kt < 15) stage(kt + 1, cur ^ 1);   // in-flight during compute

    // ---- QK^T: sacc[T] = S^T tile (rows k=32T.., cols q) , 3 rails ----
    f32x16 sacc0 = zero16(), sacc1 = zero16();
    __builtin_amdgcn_s_setprio(1);
    #pragma unroll
    for (int ds = 0; ds < 4; ds++) {
      short8 kh0 = *(const short8*)&Ksh[cur][ro0 + pc[ds]];
      short8 kh1 = *(const short8*)&Ksh[cur][ro1 + pc[ds]];
      sacc0 = __builtin_amdgcn_mfma_f32_32x32x16_bf16(kh0, qfh[ds], sacc0, 0, 0, 0);
      sacc1 = __builtin_amdgcn_mfma_f32_32x32x16_bf16(kh1, qfh[ds], sacc1, 0, 0, 0);
      sacc0 = __builtin_amdgcn_mfma_f32_32x32x16_bf16(kh0, qfl[ds], sacc0, 0, 0, 0);
      sacc1 = __builtin_amdgcn_mfma_f32_32x32x16_bf16(kh1, qfl[ds], sacc1, 0, 0, 0);
      short8 kl0 = *(const short8*)&Ksl[cur][ro0 + pc[ds]];
      short8 kl1 = *(const short8*)&Ksl[cur][ro1 + pc[ds]];
      sacc0 = __builtin_amdgcn_mfma_f32_32x32x16_bf16(kl0, qfh[ds], sacc0, 0, 0, 0);
      sacc1 = __builtin_amdgcn_mfma_f32_32x32x16_bf16(kl1, qfh[ds], sacc1, 0, 0, 0);
    }
    __builtin_amdgcn_s_setprio(0);

    // ---- in-register online softmax (q = l31; reduce across hi-halves) ----
    float mx = -1e30f;
    #pragma unroll
    for (int r = 0; r < 16; r++) {
      mx = fmaxf(mx, sacc0[r]);
      mx = fmaxf(mx, sacc1[r]);
    }
    mx = fmaxf(mx, __shfl_xor(mx, 32));
    float mnew = fmaxf(m_i, mx);
    float mL = mnew * LOG2E;
    float alpha = exp2f(fmaf(m_i, LOG2E, -mL));
    float sum = 0.f;
    unsigned pw[16];
    #pragma unroll
    for (int j = 0; j < 8; j++) {
      float p0 = exp2f(fmaf(sacc0[2 * j], LOG2E, -mL));
      float p1 = exp2f(fmaf(sacc0[2 * j + 1], LOG2E, -mL));
      sum += p0 + p1;
      asm("v_cvt_pk_bf16_f32 %0, %1, %2" : "=v"(pw[j]) : "v"(p0), "v"(p1));
    }
    #pragma unroll
    for (int j = 0; j < 8; j++) {
      float p0 = exp2f(fmaf(sacc1[2 * j], LOG2E, -mL));
      float p1 = exp2f(fmaf(sacc1[2 * j + 1], LOG2E, -mL));
      sum += p0 + p1;
      asm("v_cvt_pk_bf16_f32 %0, %1, %2" : "=v"(pw[8 + j]) : "v"(p0), "v"(p1));
    }
    sum += __shfl_xor(sum, 32);
    l_i = fmaf(l_i, alpha, sum);
    m_i = mnew;
    #pragma unroll
    for (int r = 0; r < 16; r++) {
      oacc[0][r] *= alpha;
      oacc[1][r] *= alpha;
    }

    // ---- PV: oacc[dt] += mfma32(V^T-frag, P-frag) ----
    __builtin_amdgcn_s_setprio(1);
    #pragma unroll
    for (int ks = 0; ks < 4; ks++) {
      const int base = (ks >> 1) * 8 + (ks & 1) * 4;
      uint2v s0 = __builtin_amdgcn_permlane32_swap(pw[base + 0], pw[base + 2], false, false);
      uint2v s1 = __builtin_amdgcn_permlane32_swap(pw[base + 1], pw[base + 3], false, false);
      short8 pfrag = u4s8((uint4v){s0.x, s1.x, s0.y, s1.y});
      short8 vf0 = *(const short8*)&VTs[cur][ro0 + pc[ks]];
      short8 vf1 = *(const short8*)&VTs[cur][ro1 + pc[ks]];
      oacc[0] = __builtin_amdgcn_mfma_f32_32x32x16_bf16(vf0, pfrag, oacc[0], 0, 0, 0);
      oacc[1] = __builtin_amdgcn_mfma_f32_32x32x16_bf16(vf1, pfrag, oacc[1], 0, 0, 0);
    }
    __builtin_amdgcn_s_setprio(0);

    if (kt < 15) __syncthreads();   // drains next-tile DMA + releases cur buf
  }

  // ---- epilogue: lane-local 1/l, uint2 stores ----
  const int b = bh >> 3, h = bh & 7;
  const int n = qrow0 + l31;
  float rinv = 1.f / l_i;
  #pragma unroll
  for (int dt = 0; dt < 2; dt++) {
    #pragma unroll
    for (int t = 0; t < 4; t++) {
      ushort_t hv[4], lv[4];
      #pragma unroll
      for (int e = 0; e < 4; e++) {
        float x = oacc[dt][4 * t + e] * rinv;
        hv[e] = f2bf(x);
        lv[e] = f2bf(x - bf2f(hv[e]));
      }
      size_t idx = (size_t)(b * 1024 + n) * 512 + h * 64 + dt * 32 + t * 8 + hi * 4;
      *(uint2v*)&obh[idx] = (uint2v){(unsigned)hv[0] | ((unsigned)hv[1] << 16),
                                     (unsigned)hv[2] | ((unsigned)hv[3] << 16)};
      *(uint2v*)&obl[idx] = (uint2v){(unsigned)lv[0] | ((unsigned)lv[1] << 16),
                                     (unsigned)lv[2] | ((unsigned)lv[3] << 16)};
    }
  }
}

// ---------------- launcher ----------------
extern "C" void kernel_launch(void* const* d_in, const int* in_sizes, int n_in,
                              void* d_out, int out_size, void* d_ws, size_t ws_size,
                              hipStream_t stream) {
  const float* cur = (const float*)d_in[0];   // [8,1024,512] fp32
  const float* hid = (const float*)d_in[1];   // [8,1024,512] fp32
  const float* Wq  = (const float*)d_in[2];   // [512,512]
  const float* Wkv = (const float*)d_in[3];   // [512,1024]
  const float* Wo  = (const float*)d_in[4];   // [512,512]

  ushort_t* ws = (ushort_t*)d_ws;
  ushort_t* Ch = ws;                    // 4,194,304  (cur split; reused: aout hi)
  ushort_t* Cl = Ch + 4194304;          // 4,194,304  (cur split; reused: aout lo)
  ushort_t* Hh = Cl + 4194304;          // 4,194,304  (hid split)
  ushort_t* Hl = Hh + 4194304;          // 4,194,304
  ushort_t* kh = Hl + 4194304;          // 4,194,304
  ushort_t* kl = kh + 4194304;          // 4,194,304
  ushort_t* vt = kl + 4194304;          // 4,194,304
  ushort_t* qhb = vt + 4194304;         // 4,194,304
  ushort_t* qlb = qhb + 4194304;        // 4,194,304
  ushort_t* WqTh = qlb + 4194304;       // 262,144
  ushort_t* WqTl = WqTh + 262144;       // 262,144
  ushort_t* WkvTh = WqTl + 262144;      // 524,288
  ushort_t* WkvTl = WkvTh + 524288;     // 524,288
  ushort_t* WoTh = WkvTl + 524288;      // 262,144
  ushort_t* WoTl = WoTh + 262144;       // 262,144

  // merged ingest: weight transpose (blocks 0..1023) + activation split (1024..5119)
  prep_all<<<5120, 256, 0, stream>>>(cur, hid, Wq, Wkv, Wo,
                                     Ch, Cl, Hh, Hl,
                                     WqTh, WqTl, WkvTh, WkvTl, WoTh, WoTl);

  // kv projection: BM=64, BN=128 -> grid (8,128) = 1024 blocks
  gemm3_bt<1, 2, 4><<<dim3(8, 128), 256, 0, stream>>>(Hh, Hl, WkvTh, WkvTl,
                                                      kh, kl, vt, (float*)nullptr, 512, 0);
  // q projection: BM=64, BN=128 -> grid (4,128) = 512 blocks
  gemm3_bt<0, 2, 4><<<dim3(4, 128), 256, 0, stream>>>(Ch, Cl, WqTh, WqTl,
                                                      qhb, qlb, (ushort_t*)nullptr, (float*)nullptr, 512, 0);
  // attention: 512 blocks (head-major XCD grouping), 128 q-rows/block
  flash_attn<<<512, 256, 0, stream>>>(qhb, qlb, kh, kl, vt, Ch, Cl);
  // output projection: BM=64, BN=128 -> grid (4,128) = 512 blocks -> fp32 d_out
  gemm3_bt<2, 2, 4><<<dim3(4, 128), 256, 0, stream>>>(Ch, Cl, WoTh, WoTl,
                                                      (ushort_t*)nullptr, (ushort_t*)nullptr,
                                                      (ushort_t*)nullptr, (float*)d_out, 512, 512);
}

// Round 5
// 216.376 us; speedup vs baseline: 1.1601x; 1.0474x over previous
//
#include <hip/hip_runtime.h>

typedef unsigned short ushort_t;
typedef __attribute__((ext_vector_type(8))) short short8;
typedef __attribute__((ext_vector_type(4))) float f32x4;
typedef __attribute__((ext_vector_type(16))) float f32x16;
typedef __attribute__((ext_vector_type(2))) unsigned uint2v;
typedef __attribute__((ext_vector_type(4))) unsigned uint4v;

#define LOG2E 1.44269504088896f

// async global->LDS, 16B per lane. LDS dest must be wave-uniform base + lane*16.
__device__ __forceinline__ void async16(const void* g, void* l) {
  __builtin_amdgcn_global_load_lds(
      (const __attribute__((address_space(1))) void*)g,
      (__attribute__((address_space(3))) void*)l, 16, 0, 0);
}

__device__ __forceinline__ ushort_t f2bf(float f) {
  union { float f; unsigned u; } x; x.f = f;
  unsigned u = x.u;
  u += 0x7fffu + ((u >> 16) & 1u);
  return (ushort_t)(u >> 16);
}

__device__ __forceinline__ float bf2f(ushort_t w) {
  union { unsigned u; float f; } x; x.u = ((unsigned)w) << 16;
  return x.f;
}

__device__ __forceinline__ short8 u4s8(uint4v u) { union { uint4v a; short8 b; } c; c.a = u; return c.b; }
__device__ __forceinline__ uint4v s8u4(short8 s) { union { short8 a; uint4v b; } c; c.a = s; return c.b; }
__device__ __forceinline__ unsigned fu(float f) { union { float a; unsigned b; } c; c.a = f; return c.b; }

__device__ __forceinline__ f32x16 zero16() {
  f32x16 v;
  #pragma unroll
  for (int i = 0; i < 16; i++) v[i] = 0.f;
  return v;
}

// ------------- merged ingest: weight transpose+split AND activation split ----
__global__ __launch_bounds__(256) void prep_all(const float* __restrict__ cur,
                                                const float* __restrict__ hid,
                                                const float* __restrict__ Wq,
                                                const float* __restrict__ Wkv,
                                                const float* __restrict__ Wo,
                                                ushort_t* __restrict__ ch, ushort_t* __restrict__ cl,
                                                ushort_t* __restrict__ hh, ushort_t* __restrict__ hl,
                                                ushort_t* __restrict__ qh, ushort_t* __restrict__ ql,
                                                ushort_t* __restrict__ kvh, ushort_t* __restrict__ kvl,
                                                ushort_t* __restrict__ oh, ushort_t* __restrict__ ol) {
  __shared__ float tile[32][33];
  int bid = blockIdx.x;
  if (bid >= 1024) {
    // ---- activation split path ----
    int i = (bid - 1024) * 256 + threadIdx.x;       // 0 .. 2*524288-1
    const float* src;
    ushort_t *hi, *lo;
    int j;
    if (i < 524288) { src = cur; hi = ch; lo = cl; j = i; }
    else            { src = hid; hi = hh; lo = hl; j = i - 524288; }
    const f32x4* s = (const f32x4*)src;
    f32x4 a = s[j * 2], b = s[j * 2 + 1];
    short8 ohh, oll;
    #pragma unroll
    for (int k = 0; k < 4; k++) {
      ushort_t h = f2bf(a[k]); ohh[k] = (short)h; oll[k] = (short)f2bf(a[k] - bf2f(h));
      h = f2bf(b[k]); ohh[k + 4] = (short)h; oll[k + 4] = (short)f2bf(b[k] - bf2f(h));
    }
    ((short8*)hi)[j] = ohh;
    ((short8*)lo)[j] = oll;
    return;
  }
  // ---- weight transpose+split path ----
  const float* src; ushort_t *dh, *dl; int Nn, bx, by;
  const int K = 512;
  if (bid < 256)      { src = Wq;  dh = qh;  dl = ql;  Nn = 512;  bx = (bid & 15) * 32; by = (bid >> 4) * 32; }
  else if (bid < 768) { int b = bid - 256; src = Wkv; dh = kvh; dl = kvl; Nn = 1024; bx = (b & 31) * 32; by = (b >> 5) * 32; }
  else                { int b = bid - 768; src = Wo;  dh = oh;  dl = ol;  Nn = 512;  bx = (b & 15) * 32; by = (b >> 4) * 32; }
  int tx = threadIdx.x & 31, ty = threadIdx.x >> 5;   // (32, 8)
  #pragma unroll
  for (int i = 0; i < 32; i += 8)
    tile[ty + i][tx] = src[(size_t)(by + ty + i) * Nn + bx + tx];
  __syncthreads();
  #pragma unroll
  for (int i = 0; i < 32; i += 8) {
    float v = tile[tx][ty + i];
    ushort_t h = f2bf(v);
    size_t idx = (size_t)(bx + ty + i) * K + by + tx;
    dh[idx] = h;
    dl[idx] = f2bf(v - bf2f(h));
  }
}

// ---- split GEMM body: C = (Ah+Al)[M][K] @ (Bh+Bl)[Nn][K]^T, 3-product ----
// BM=64, BN=128, 4 waves (2x2); wave tile 32x64. T4 counted-vmcnt pipeline:
// stage(t+1) -> vmcnt(6) [t landed, t+1 in flight] -> barrier -> compute(t)
// -> lgkmcnt(0)+barrier [readers done before t+2's overwrite].
template<int EPI>
__device__ __forceinline__ void gemm3_body(const ushort_t* __restrict__ Ah,
                                           const ushort_t* __restrict__ Al,
                                           const ushort_t* __restrict__ Bh,
                                           const ushort_t* __restrict__ Bl,
                                           ushort_t* __restrict__ o_hi,
                                           ushort_t* __restrict__ o_lo,
                                           ushort_t* __restrict__ o_vt,
                                           float* __restrict__ outf,
                                           int K, int ldo, int m0, int n0,
                                           ushort_t* lds) {
  constexpr int MT = 2, TN = 4;
  ushort_t* Ash = lds;            // [2][2048]
  ushort_t* Asl = lds + 4096;     // [2][2048]
  ushort_t* Bsh = lds + 8192;     // [2][4096]
  ushort_t* Bsl = lds + 16384;    // [2][4096]
  const int tid = threadIdx.x;
  const int wave = tid >> 6, lane = tid & 63;
  const int wm = (wave >> 1) * 32, wn = (wave & 1) * 64;
  const int lrow = lane & 15, lq = lane >> 4;

  f32x4 acc[MT][TN];
  const f32x4 z = {0.f, 0.f, 0.f, 0.f};
  #pragma unroll
  for (int i = 0; i < MT; i++)
    #pragma unroll
    for (int j = 0; j < TN; j++) acc[i][j] = z;

  auto stage = [&](int k0, int d) {
    const int aoff = d * 2048, boff = d * 4096;
    {                                     // A tile: 64 rows x 4 chunks
      int r = tid >> 2, kc = tid & 3;
      size_t ga = (size_t)(m0 + r) * K + k0 + kc * 8;
      async16(&Ah[ga], &Ash[aoff + tid * 8]);
      async16(&Al[ga], &Asl[aoff + tid * 8]);
    }
    #pragma unroll
    for (int i = 0; i < 2; i++) {         // B tile: 128 rows x 4 chunks
      int g = i * 256 + tid;
      int r = g >> 2, kc = g & 3;
      size_t gb = (size_t)(n0 + r) * K + k0 + kc * 8;
      async16(&Bh[gb], &Bsh[boff + g * 8]);
      async16(&Bl[gb], &Bsl[boff + g * 8]);
    }
  };

  stage(0, 0);
  int cur = 0;
  for (int k0 = 0; k0 < K; k0 += 32) {
    if (k0 + 32 < K) {
      stage(k0 + 32, cur ^ 1);   // 6 loads/thread, stay in flight across barrier
      asm volatile("s_waitcnt vmcnt(6)" ::: "memory");   // tile k0 landed
    } else {
      asm volatile("s_waitcnt vmcnt(0)" ::: "memory");
    }
    __builtin_amdgcn_s_barrier();

    const int ab = cur * 2048, bb = cur * 4096;
    short8 afh[MT], bfr[TN];
    #pragma unroll
    for (int t = 0; t < MT; t++)
      afh[t] = *(const short8*)&Ash[ab + (wm + t * 16 + lrow) * 32 + lq * 8];
    #pragma unroll
    for (int t = 0; t < TN; t++)
      bfr[t] = *(const short8*)&Bsh[bb + (wn + t * 16 + lrow) * 32 + lq * 8];
    #pragma unroll
    for (int ti = 0; ti < MT; ti++)
      #pragma unroll
      for (int tj = 0; tj < TN; tj++)
        acc[ti][tj] = __builtin_amdgcn_mfma_f32_16x16x32_bf16(afh[ti], bfr[tj], acc[ti][tj], 0, 0, 0);

    {
      short8 afl[MT];
      #pragma unroll
      for (int t = 0; t < MT; t++)
        afl[t] = *(const short8*)&Asl[ab + (wm + t * 16 + lrow) * 32 + lq * 8];
      #pragma unroll
      for (int ti = 0; ti < MT; ti++)
        #pragma unroll
        for (int tj = 0; tj < TN; tj++)
          acc[ti][tj] = __builtin_amdgcn_mfma_f32_16x16x32_bf16(afl[ti], bfr[tj], acc[ti][tj], 0, 0, 0);
    }
    #pragma unroll
    for (int t = 0; t < TN; t++)
      bfr[t] = *(const short8*)&Bsl[bb + (wn + t * 16 + lrow) * 32 + lq * 8];
    #pragma unroll
    for (int ti = 0; ti < MT; ti++)
      #pragma unroll
      for (int tj = 0; tj < TN; tj++)
        acc[ti][tj] = __builtin_amdgcn_mfma_f32_16x16x32_bf16(afh[ti], bfr[tj], acc[ti][tj], 0, 0, 0);

    if (k0 + 32 < K) {   // readers done before next iter's stage overwrites buf
      asm volatile("s_waitcnt lgkmcnt(0)" ::: "memory");
      __builtin_amdgcn_s_barrier();
    }
    cur ^= 1;
  }

  // epilogue
  #pragma unroll
  for (int ti = 0; ti < MT; ti++) {
    #pragma unroll
    for (int tj = 0; tj < TN; tj++) {
      int row0 = m0 + wm + ti * 16 + lq * 4;
      int col = n0 + wn + tj * 16 + lrow;
      #pragma unroll
      for (int r = 0; r < 4; r++) {
        int m = row0 + r;
        float fv = acc[ti][tj][r];
        if (EPI == 0) {
          size_t idx = (size_t)((m >> 10) * 8 + (col >> 6)) * 65536 + (m & 1023) * 64 + (col & 63);
          ushort_t h = f2bf(fv);
          o_hi[idx] = h;
          o_lo[idx] = f2bf(fv - bf2f(h));
        } else if (EPI == 1) {
          if (col < 512) {
            size_t idx = (size_t)((m >> 10) * 8 + (col >> 6)) * 65536 + (m & 1023) * 64 + (col & 63);
            ushort_t h = f2bf(fv);
            o_hi[idx] = h;
            o_lo[idx] = f2bf(fv - bf2f(h));
          } else {
            int cc = col - 512;
            o_vt[(size_t)(((m >> 10) * 8 + (cc >> 6)) * 64 + (cc & 63)) * 1024 + (m & 1023)] = f2bf(fv);
          }
        } else {
          outf[(size_t)m * ldo + col] = fv;   // fp32 final output
        }
      }
    }
  }
}

// merged q+kv projection: 1536 blocks, XCD-bijective remap (1536 = 8*192).
// w < 1024 -> kv (grid 8x128), w >= 1024 -> q (grid 4x128). Block-uniform branch.
__global__ __launch_bounds__(256) void gemm_qkv(const ushort_t* __restrict__ Hh,
                                                const ushort_t* __restrict__ Hl,
                                                const ushort_t* __restrict__ WkvTh,
                                                const ushort_t* __restrict__ WkvTl,
                                                ushort_t* __restrict__ kh,
                                                ushort_t* __restrict__ kl,
                                                ushort_t* __restrict__ vt,
                                                const ushort_t* __restrict__ Chp,
                                                const ushort_t* __restrict__ Clp,
                                                const ushort_t* __restrict__ WqTh,
                                                const ushort_t* __restrict__ WqTl,
                                                ushort_t* __restrict__ qhb,
                                                ushort_t* __restrict__ qlb) {
  __shared__ __align__(16) ushort_t lds[24576];
  int bid = blockIdx.x;
  int w = (bid & 7) * 192 + (bid >> 3);      // contiguous work per XCD
  if (w < 1024) {
    int n0 = (w & 7) * 128, m0 = (w >> 3) * 64;
    gemm3_body<1>(Hh, Hl, WkvTh, WkvTl, kh, kl, vt, (float*)nullptr, 512, 0, m0, n0, lds);
  } else {
    int ww = w - 1024;
    int n0 = (ww & 3) * 128, m0 = (ww >> 2) * 64;
    gemm3_body<0>(Chp, Clp, WqTh, WqTl, qhb, qlb, (ushort_t*)nullptr, (float*)nullptr, 512, 0, m0, n0, lds);
  }
}

// output projection: 512 blocks, XCD-bijective remap (512 = 8*64), fp32 out.
__global__ __launch_bounds__(256) void gemm_o(const ushort_t* __restrict__ Ah,
                                              const ushort_t* __restrict__ Al,
                                              const ushort_t* __restrict__ Bh,
                                              const ushort_t* __restrict__ Bl,
                                              float* __restrict__ outf) {
  __shared__ __align__(16) ushort_t lds[24576];
  int bid = blockIdx.x;
  int w = (bid & 7) * 64 + (bid >> 3);
  int n0 = (w & 3) * 128, m0 = (w >> 2) * 64;
  gemm3_body<2>(Ah, Al, Bh, Bl, (ushort_t*)nullptr, (ushort_t*)nullptr,
                (ushort_t*)nullptr, outf, 512, 512, m0, n0, lds);
}

// ---------------- flash attention v5 + counted-vmcnt pipeline ----------
// 512 blocks: bh = blk & 63 (all 8 q-tiles of a head share blk%8 -> one XCD).
// 4 waves x 32 q-rows. QK^T swapped (S^T via mfma32(K,Q)); in-register softmax;
// P via cvt_pk + permlane32_swap; PV swapped (O^T via mfma32(V^T,P)).
// K/V staged via global_load_lds, pre-swizzled source (chunk ^= row&7).
// T4: stage(t+1); vmcnt(6); barrier; compute(t); lgkmcnt(0); barrier.
__global__ __launch_bounds__(256, 2) void flash_attn(const ushort_t* __restrict__ qh,
                                                     const ushort_t* __restrict__ ql,
                                                     const ushort_t* __restrict__ kh,
                                                     const ushort_t* __restrict__ kl,
                                                     const ushort_t* __restrict__ vtb,
                                                     ushort_t* __restrict__ obh,
                                                     ushort_t* __restrict__ obl) {
  __shared__ __align__(16) ushort_t Ksh[2][64 * 64];
  __shared__ __align__(16) ushort_t Ksl[2][64 * 64];
  __shared__ __align__(16) ushort_t VTs[2][64 * 64];

  const int tid = threadIdx.x;
  const int wave = tid >> 6, lane = tid & 63;
  const int bh = blockIdx.x & 63, qt = blockIdx.x >> 6;
  const int l31 = lane & 31, hi = lane >> 5;

  const ushort_t* Qh = qh + (size_t)bh * 65536;
  const ushort_t* Ql = ql + (size_t)bh * 65536;
  const ushort_t* Kph = kh + (size_t)bh * 65536;
  const ushort_t* Kpl = kl + (size_t)bh * 65536;
  const ushort_t* VT = vtb + (size_t)bh * 65536;

  const int qrow0 = qt * 128 + wave * 32;

  // Q fragments (B-operand: col q = l31, contraction d = ds*16 + hi*8 + 0..7)
  short8 qfh[4], qfl[4];
  #pragma unroll
  for (int ds = 0; ds < 4; ds++) {
    size_t idx = (size_t)(qrow0 + l31) * 64 + ds * 16 + hi * 8;
    qfh[ds] = *(const short8*)&Qh[idx];
    qfl[ds] = *(const short8*)&Ql[idx];
  }

  f32x16 oacc[2];                 // O^T: [dtile]; row d, col q = l31
  oacc[0] = zero16();
  oacc[1] = zero16();
  float m_i = -1e30f, l_i = 0.f;  // per q = qrow0 + l31 (replicated over hi)

  // swizzled-read offsets: phys chunk = (2*i + hi) ^ (l31 & 7); i = ds or ks
  const int r7 = l31 & 7;
  int pc[4];
  #pragma unroll
  for (int i = 0; i < 4; i++) pc[i] = (((2 * i + hi) ^ r7) << 3);
  const int ro0 = l31 * 64, ro1 = ro0 + 2048;   // rows l31 and 32+l31

  // stage kt-tile into buffer d: linear LDS dest, inverse-swizzled global src
  auto stage = [&](int kt, int d) {
    #pragma unroll
    for (int i = 0; i < 2; i++) {
      int g = i * 256 + tid, rw = g >> 3, ch = g & 7;
      int co = ((ch ^ (rw & 7)) << 3);           // swizzled source column
      int lofs = rw * 64 + (ch << 3);            // linear LDS offset
      size_t kidx = (size_t)(kt * 64 + rw) * 64 + co;
      async16(&Kph[kidx], &Ksh[d][lofs]);
      async16(&Kpl[kidx], &Ksl[d][lofs]);
      async16(&VT[(size_t)rw * 1024 + kt * 64 + co], &VTs[d][lofs]);
    }
  };

  stage(0, 0);

  for (int kt = 0; kt < 16; kt++) {
    const int cur = kt & 1;
    if (kt < 15) {
      stage(kt + 1, cur ^ 1);     // 6 loads/thread, in flight across barrier
      asm volatile("s_waitcnt vmcnt(6)" ::: "memory");   // tile kt landed
    } else {
      asm volatile("s_waitcnt vmcnt(0)" ::: "memory");
    }
    __builtin_amdgcn_s_barrier();

    // ---- QK^T: sacc[T] = S^T tile (rows k=32T.., cols q) , 3 rails ----
    f32x16 sacc0 = zero16(), sacc1 = zero16();
    __builtin_amdgcn_s_setprio(1);
    #pragma unroll
    for (int ds = 0; ds < 4; ds++) {
      short8 kh0 = *(const short8*)&Ksh[cur][ro0 + pc[ds]];
      short8 kh1 = *(const short8*)&Ksh[cur][ro1 + pc[ds]];
      sacc0 = __builtin_amdgcn_mfma_f32_32x32x16_bf16(kh0, qfh[ds], sacc0, 0, 0, 0);
      sacc1 = __builtin_amdgcn_mfma_f32_32x32x16_bf16(kh1, qfh[ds], sacc1, 0, 0, 0);
      sacc0 = __builtin_amdgcn_mfma_f32_32x32x16_bf16(kh0, qfl[ds], sacc0, 0, 0, 0);
      sacc1 = __builtin_amdgcn_mfma_f32_32x32x16_bf16(kh1, qfl[ds], sacc1, 0, 0, 0);
      short8 kl0 = *(const short8*)&Ksl[cur][ro0 + pc[ds]];
      short8 kl1 = *(const short8*)&Ksl[cur][ro1 + pc[ds]];
      sacc0 = __builtin_amdgcn_mfma_f32_32x32x16_bf16(kl0, qfh[ds], sacc0, 0, 0, 0);
      sacc1 = __builtin_amdgcn_mfma_f32_32x32x16_bf16(kl1, qfh[ds], sacc1, 0, 0, 0);
    }
    __builtin_amdgcn_s_setprio(0);

    // ---- in-register online softmax (q = l31; reduce across hi-halves) ----
    float mx = -1e30f;
    #pragma unroll
    for (int r = 0; r < 16; r++) {
      mx = fmaxf(mx, sacc0[r]);
      mx = fmaxf(mx, sacc1[r]);
    }
    mx = fmaxf(mx, __shfl_xor(mx, 32));
    float mnew = fmaxf(m_i, mx);
    float mL = mnew * LOG2E;
    float alpha = exp2f(fmaf(m_i, LOG2E, -mL));
    float sum = 0.f;
    unsigned pw[16];
    #pragma unroll
    for (int j = 0; j < 8; j++) {
      float p0 = exp2f(fmaf(sacc0[2 * j], LOG2E, -mL));
      float p1 = exp2f(fmaf(sacc0[2 * j + 1], LOG2E, -mL));
      sum += p0 + p1;
      asm("v_cvt_pk_bf16_f32 %0, %1, %2" : "=v"(pw[j]) : "v"(p0), "v"(p1));
    }
    #pragma unroll
    for (int j = 0; j < 8; j++) {
      float p0 = exp2f(fmaf(sacc1[2 * j], LOG2E, -mL));
      float p1 = exp2f(fmaf(sacc1[2 * j + 1], LOG2E, -mL));
      sum += p0 + p1;
      asm("v_cvt_pk_bf16_f32 %0, %1, %2" : "=v"(pw[8 + j]) : "v"(p0), "v"(p1));
    }
    sum += __shfl_xor(sum, 32);
    l_i = fmaf(l_i, alpha, sum);
    m_i = mnew;
    #pragma unroll
    for (int r = 0; r < 16; r++) {
      oacc[0][r] *= alpha;
      oacc[1][r] *= alpha;
    }

    // ---- PV: oacc[dt] += mfma32(V^T-frag, P-frag) ----
    __builtin_amdgcn_s_setprio(1);
    #pragma unroll
    for (int ks = 0; ks < 4; ks++) {
      const int base = (ks >> 1) * 8 + (ks & 1) * 4;
      uint2v s0 = __builtin_amdgcn_permlane32_swap(pw[base + 0], pw[base + 2], false, false);
      uint2v s1 = __builtin_amdgcn_permlane32_swap(pw[base + 1], pw[base + 3], false, false);
      short8 pfrag = u4s8((uint4v){s0.x, s1.x, s0.y, s1.y});
      short8 vf0 = *(const short8*)&VTs[cur][ro0 + pc[ks]];
      short8 vf1 = *(const short8*)&VTs[cur][ro1 + pc[ks]];
      oacc[0] = __builtin_amdgcn_mfma_f32_32x32x16_bf16(vf0, pfrag, oacc[0], 0, 0, 0);
      oacc[1] = __builtin_amdgcn_mfma_f32_32x32x16_bf16(vf1, pfrag, oacc[1], 0, 0, 0);
    }
    __builtin_amdgcn_s_setprio(0);

    if (kt < 15) {   // readers done before next iter's stage overwrites buf
      asm volatile("s_waitcnt lgkmcnt(0)" ::: "memory");
      __builtin_amdgcn_s_barrier();
    }
  }

  // ---- epilogue: lane-local 1/l, uint2 stores ----
  const int b = bh >> 3, h = bh & 7;
  const int n = qrow0 + l31;
  float rinv = 1.f / l_i;
  #pragma unroll
  for (int dt = 0; dt < 2; dt++) {
    #pragma unroll
    for (int t = 0; t < 4; t++) {
      ushort_t hv[4], lv[4];
      #pragma unroll
      for (int e = 0; e < 4; e++) {
        float x = oacc[dt][4 * t + e] * rinv;
        hv[e] = f2bf(x);
        lv[e] = f2bf(x - bf2f(hv[e]));
      }
      size_t idx = (size_t)(b * 1024 + n) * 512 + h * 64 + dt * 32 + t * 8 + hi * 4;
      *(uint2v*)&obh[idx] = (uint2v){(unsigned)hv[0] | ((unsigned)hv[1] << 16),
                                     (unsigned)hv[2] | ((unsigned)hv[3] << 16)};
      *(uint2v*)&obl[idx] = (uint2v){(unsigned)lv[0] | ((unsigned)lv[1] << 16),
                                     (unsigned)lv[2] | ((unsigned)lv[3] << 16)};
    }
  }
}

// ---------------- launcher ----------------
extern "C" void kernel_launch(void* const* d_in, const int* in_sizes, int n_in,
                              void* d_out, int out_size, void* d_ws, size_t ws_size,
                              hipStream_t stream) {
  const float* cur = (const float*)d_in[0];   // [8,1024,512] fp32
  const float* hid = (const float*)d_in[1];   // [8,1024,512] fp32
  const float* Wq  = (const float*)d_in[2];   // [512,512]
  const float* Wkv = (const float*)d_in[3];   // [512,1024]
  const float* Wo  = (const float*)d_in[4];   // [512,512]

  ushort_t* ws = (ushort_t*)d_ws;
  ushort_t* Ch = ws;                    // 4,194,304  (cur split; reused: aout hi)
  ushort_t* Cl = Ch + 4194304;          // 4,194,304  (cur split; reused: aout lo)
  ushort_t* Hh = Cl + 4194304;          // 4,194,304  (hid split)
  ushort_t* Hl = Hh + 4194304;          // 4,194,304
  ushort_t* kh = Hl + 4194304;          // 4,194,304
  ushort_t* kl = kh + 4194304;          // 4,194,304
  ushort_t* vt = kl + 4194304;          // 4,194,304
  ushort_t* qhb = vt + 4194304;         // 4,194,304
  ushort_t* qlb = qhb + 4194304;        // 4,194,304
  ushort_t* WqTh = qlb + 4194304;       // 262,144
  ushort_t* WqTl = WqTh + 262144;       // 262,144
  ushort_t* WkvTh = WqTl + 262144;      // 524,288
  ushort_t* WkvTl = WkvTh + 524288;     // 524,288
  ushort_t* WoTh = WkvTl + 524288;      // 262,144
  ushort_t* WoTl = WoTh + 262144;       // 262,144

  // merged ingest: weight transpose (blocks 0..1023) + activation split (1024..5119)
  prep_all<<<5120, 256, 0, stream>>>(cur, hid, Wq, Wkv, Wo,
                                     Ch, Cl, Hh, Hl,
                                     WqTh, WqTl, WkvTh, WkvTl, WoTh, WoTl);

  // merged kv + q projections: 1536 blocks, XCD-contiguous work
  gemm_qkv<<<1536, 256, 0, stream>>>(Hh, Hl, WkvTh, WkvTl, kh, kl, vt,
                                     Ch, Cl, WqTh, WqTl, qhb, qlb);

  // attention: 512 blocks (head-major XCD grouping), 128 q-rows/block
  flash_attn<<<512, 256, 0, stream>>>(qhb, qlb, kh, kl, vt, Ch, Cl);

  // output projection: 512 blocks -> fp32 d_out
  gemm_o<<<512, 256, 0, stream>>>(Ch, Cl, WoTh, WoTl, (float*)d_out);
}